// Round 4
// baseline (184.262 us; speedup 1.0000x reference)
//
#include <hip/hip_runtime.h>

#define NX 512
#define NY 512
#define XY (NX * NY)

typedef float f4 __attribute__((ext_vector_type(4)));

#define GLOBAL_AS __attribute__((address_space(1)))
#define LDS_AS    __attribute__((address_space(3)))

// Persistent rolling-window version.
// 512 blocks (exactly 2/CU, 60 KB LDS) x 512 threads; each block owns 8
// consecutive 4-row strips of one batch (XCD-chunked). s is kept in a rolling
// mod-8 row window in LDS (slot = x & 7): per strip only the 4 NEW rows are
// staged (global reads drop 196 MB -> ~110 MB; no ge register rows at all).
// Per strip: A [phase2: b from s_lds, retain ce/up/dn/pv3/nx0 in regs] B
// [issue stage(k+1) via global_load_lds; phase3 from retained regs + b_lds].
// Hazards: stage(k+1) writes slots == x0-2..x0+1, which phase3 never reads
// (b_lds + registers only); barrier B orders it after phase2(k)'s s-reads,
// barrier A(k+1) (vmcnt(0)-draining __syncthreads) before phase2(k+1).
// launch_bounds(512,4): VGPR cap 128 >= ~100 peak -> no spills (r2 lesson).
__global__ __launch_bounds__(512, 4) void psi11t_kernel(
    const float* __restrict__ s,
    const float* __restrict__ t,
    const float* __restrict__ c0,
    float* __restrict__ out)
{
    __shared__ __align__(16) float s_lds[3 * 8 * NY];  // [c][slot][y], slot = x & 7
    __shared__ __align__(16) float b_lds[6 * NY];      // [row][y], row <-> x0-1+row

    const int tid = threadIdx.x;
    const int r   = tid >> 7;                 // 0..3: output row within strip
    const int yb  = (tid & 127) * 4;
    const int ybm = (yb + NY - 4) & (NY - 1); // aligned f4 at y-4 (wrap)
    const int ybp = (yb + 4) & (NY - 1);      // aligned f4 at y+4 (wrap)
    const bool lo256 = (tid < 256);

    // XCD chunking: XCD (blockIdx&7) owns gids [xcd*512, xcd*512+512) = 4 whole
    // batches; block j takes 8 consecutive strips (stays inside one batch).
    const int xcd = blockIdx.x & 7;
    const int j   = blockIdx.x >> 3;          // 0..63
    const int g0  = xcd * 512 + j * 8;
    const int bidx = g0 >> 7;
    const int x00  = (g0 & 127) * 4;

    const float* sb  = s   + (size_t)bidx * 3 * XY;
    float*       ob0 = out + (size_t)bidx * 3 * XY;

    // ---- prologue: stage s rows x00-2 .. x00+5 (8 rows x 3 comps, 48 KB) ----
    #pragma unroll
    for (int q = 0; q < 6; ++q) {
        const int c  = q >> 1;
        const int x  = x00 - 2 + r + 4 * (q & 1) + NX;
        const int xg = x & (NX - 1);
        const int sl = x & 7;
        __builtin_amdgcn_global_load_lds(
            (const GLOBAL_AS void*)(sb + (size_t)c * XY + (size_t)xg * NY + yb),
            (LDS_AS void*)&s_lds[(c * 8 + sl) * NY + yb], 16, 0, 0);
    }

    const float coeff = 2.0f * t[0] * c0[0];

    for (int i = 0; i < 8; ++i) {
        const int x0 = x00 + 4 * i;
        __syncthreads();                      // A: staged rows landed; b_lds free

        // ---- phase 2: b rows 1..4 (all threads); retain minimal s-fragments
        const int sU = (x0 + r - 1 + NX) & 7;
        const int sC = (x0 + r) & 7;
        const int sD = (x0 + r + 1) & 7;
        f4 ce[3], up[3], dn[3];
        float pv3[3], nx0[3];
        f4 bc = {0.f, 0.f, 0.f, 0.f};
        #pragma unroll
        for (int c = 0; c < 3; ++c) {
            const float* SC = &s_lds[(c * 8 + sC) * NY];
            up[c] = *(const f4*)&s_lds[(c * 8 + sU) * NY + yb];
            ce[c] = *(const f4*)(SC + yb);
            dn[c] = *(const f4*)&s_lds[(c * 8 + sD) * NY + yb];
            const f4 pv = *(const f4*)(SC + ybm);
            const f4 nx = *(const f4*)(SC + ybp);
            pv3[c] = pv[3];
            nx0[c] = nx[0];
            const f4 shl = {pv[3], ce[c][0], ce[c][1], ce[c][2]};
            const f4 shr = {ce[c][1], ce[c][2], ce[c][3], nx[0]};
            bc += ce[c] * (up[c] + dn[c] + shl + shr);
        }
        *(f4*)&b_lds[(r + 1) * NY + yb] = bc;

        // halo b rows 0 and 5 (waves 0-3; wave-uniform branches)
        if (lo256) {
            const int xh = (tid < 128) ? (x0 - 1 + NX) : (x0 + 4 + NX);
            const int hC = xh & 7, hU = (xh - 1) & 7, hD = (xh + 1) & 7;
            const int rb = (tid < 128) ? 0 : 5;
            f4 acc = {0.f, 0.f, 0.f, 0.f};
            #pragma unroll
            for (int c = 0; c < 3; ++c) {
                const float* SC = &s_lds[(c * 8 + hC) * NY];
                const f4 c2 = *(const f4*)(SC + yb);
                const f4 p2 = *(const f4*)(SC + ybm);
                const f4 n2 = *(const f4*)(SC + ybp);
                const f4 u2 = *(const f4*)&s_lds[(c * 8 + hU) * NY + yb];
                const f4 d2 = *(const f4*)&s_lds[(c * 8 + hD) * NY + yb];
                const f4 sl2 = {p2[3], c2[0], c2[1], c2[2]};
                const f4 sr2 = {c2[1], c2[2], c2[3], n2[0]};
                acc += c2 * (u2 + d2 + sl2 + sr2);
            }
            *(f4*)&b_lds[rb * NY + yb] = acc;
        }
        __syncthreads();                      // B: b ready; phase2 s-reads done

        // ---- issue next strip's 4 new rows; drains under phase3 + loop turn
        if (i < 7) {
            const int x  = x0 + 6 + r;        // rows x0+6..x0+9 (thread-row r)
            const int xg = x & (NX - 1);
            const int sl = x & 7;
            #pragma unroll
            for (int q = 0; q < 3; ++q) {     // comp = q
                __builtin_amdgcn_global_load_lds(
                    (const GLOBAL_AS void*)(sb + (size_t)q * XY + (size_t)xg * NY + yb),
                    (LDS_AS void*)&s_lds[(q * 8 + sl) * NY + yb], 16, 0, 0);
            }
        }

        // ---- phase 3: outputs from retained regs + 4x aligned b128 of b_lds
        const float* B1 = &b_lds[(r + 1) * NY];
        const f4 bu = *(const f4*)&b_lds[r * NY + yb];
        const f4 bd = *(const f4*)&b_lds[(r + 2) * NY + yb];
        const f4 bp = *(const f4*)(B1 + ybm);
        const f4 bn = *(const f4*)(B1 + ybp);
        const f4 bshl = {bp[3], bc[0], bc[1], bc[2]};
        const f4 bshr = {bc[1], bc[2], bc[3], bn[0]};

        f4 G[3];
        #pragma unroll
        for (int c = 0; c < 3; ++c) {
            const f4 shl = {pv3[c], ce[c][0], ce[c][1], ce[c][2]};
            const f4 shr = {ce[c][1], ce[c][2], ce[c][3], nx0[c]};
            const f4 Fs = up[c] + dn[c] + shl + shr;
            G[c] = Fs * bc + up[c] * bu + dn[c] * bd + shl * bshl + shr * bshr;
        }

        const f4 o0 = (ce[1] * G[2] - ce[2] * G[1]) * coeff;
        const f4 o1 = (ce[2] * G[0] - ce[0] * G[2]) * coeff;
        const f4 o2 = (ce[0] * G[1] - ce[1] * G[0]) * coeff;

        float* ob = ob0 + (size_t)(x0 + r) * NY + yb;
        __builtin_nontemporal_store(o0, (f4*)ob);
        __builtin_nontemporal_store(o1, (f4*)(ob + XY));
        __builtin_nontemporal_store(o2, (f4*)(ob + 2 * XY));
    }
}

extern "C" void kernel_launch(void* const* d_in, const int* in_sizes, int n_in,
                              void* d_out, int out_size, void* d_ws, size_t ws_size,
                              hipStream_t stream) {
    const float* s  = (const float*)d_in[0];
    const float* t  = (const float*)d_in[1];
    const float* c0 = (const float*)d_in[2];
    float* out = (float*)d_out;

    psi11t_kernel<<<512, 512, 0, stream>>>(s, t, c0, out);
}